// Round 1
// baseline (437.697 us; speedup 1.0000x reference)
//
#include <hip/hip_runtime.h>

#define H 64

typedef __attribute__((ext_vector_type(8))) __bf16 bf16x8;
typedef __attribute__((ext_vector_type(4))) float f32x4;
typedef unsigned short u16;
typedef unsigned int u32;

union F8 { bf16x8 b; u16 u[8]; uint4 q; };

__device__ __forceinline__ u16 f2bf(float f) {
    union { float f; u32 u; } v; v.f = f;
    u32 r = v.u + 0x7FFF + ((v.u >> 16) & 1);   // RNE
    return (u16)(r >> 16);
}
__device__ __forceinline__ float bf2f(u16 x) {
    return __uint_as_float((u32)x << 16);
}
// Swizzled layout: element (col,k) at byte ((col*K+k)*2) ^ ((col&7)<<4).
__device__ __forceinline__ unsigned swz(int col, int k, int K) {
    return ((unsigned)(col * K + k) * 2u) ^ (((unsigned)col & 7u) << 4);
}

// ---------------- weight convert ----------------
struct Seg { const float* src; unsigned dstBytes; int K; int N; };
struct Segs { Seg s[8]; };

__global__ __launch_bounds__(256) void conv_weights(Segs segs, char* out) {
    Seg sg = segs.s[blockIdx.y];
    int total = sg.K * sg.N;
    char* dst = out + sg.dstBytes;
    for (int e = blockIdx.x * 256 + threadIdx.x; e < total; e += gridDim.x * 256) {
        int k = e / sg.N, n = e % sg.N;
        *(u16*)(dst + swz(n, k, sg.K)) = f2bf(sg.src[e]);
    }
}

// ---------------- fused: node f32->bf16 convert + destination histogram ----------------
struct I3 { const int* idx[3]; int m[3]; };
struct CNH { const float4* src; ushort4* dst; int n4; I3 h; u32* cnt; };

__global__ __launch_bounds__(256) void conv_nodes_hist(CNH a) {
    if (blockIdx.y == 0) {
        for (int i = blockIdx.x * 256 + threadIdx.x; i < a.n4; i += gridDim.x * 256) {
            float4 f = a.src[i];
            ushort4 o;
            o.x = f2bf(f.x); o.y = f2bf(f.y); o.z = f2bf(f.z); o.w = f2bf(f.w);
            a.dst[i] = o;
        }
    } else {
        const int r = blockIdx.y - 1;
        const int* idx = a.h.idx[r];
        const int M = a.h.m[r];
        for (int i = blockIdx.x * 256 + threadIdx.x; i < M; i += gridDim.x * 256)
            atomicAdd(a.cnt + idx[i], 1u);
    }
}

// ---------------- scan (3 kernels); scan_add2 emits base AND the rank cursor ----------------
__global__ __launch_bounds__(512) void scan_blocks(u32* __restrict__ data,
                                                   u32* __restrict__ sums, int n) {
    __shared__ u32 s[512];
    int tid = threadIdx.x, i = blockIdx.x * 512 + tid;
    u32 v = (i < n) ? data[i] : 0u;
    s[tid] = v; __syncthreads();
    for (int d = 1; d < 512; d <<= 1) {
        u32 t = (tid >= d) ? s[tid - d] : 0u; __syncthreads();
        s[tid] += t; __syncthreads();
    }
    if (i < n) data[i] = s[tid] - v;               // exclusive
    if (tid == 511) sums[blockIdx.x] = s[511];
}

__global__ __launch_bounds__(512) void scan_sums(u32* __restrict__ sums, int nb) {
    __shared__ u32 s[512];
    int tid = threadIdx.x;
    u32 v = (tid < nb) ? sums[tid] : 0u;
    s[tid] = v; __syncthreads();
    for (int d = 1; d < 512; d <<= 1) {
        u32 t = (tid >= d) ? s[tid - d] : 0u; __syncthreads();
        s[tid] += t; __syncthreads();
    }
    if (tid < nb) sums[tid] = s[tid] - v;          // exclusive
}

__global__ __launch_bounds__(512) void scan_add2(u32* __restrict__ data,
                                                 u32* __restrict__ off,
                                                 const u32* __restrict__ sums, int n) {
    int i = blockIdx.x * 512 + threadIdx.x;
    if (i < n) { u32 v = data[i] + sums[blockIdx.x]; data[i] = v; off[i] = v; }
}

// pos[segOff + i] = sorted slot of message i of relation blockIdx.y
__global__ __launch_bounds__(256) void rank_all(I3 h, u32* __restrict__ off,
                                                u32* __restrict__ pos) {
    const int r = blockIdx.y;
    const int* idx = h.idx[r];
    const int M = h.m[r];
    u32* p = pos;
    for (int q = 0; q < r; ++q) p += h.m[q];
    for (int i = blockIdx.x * 256 + threadIdx.x; i < M; i += gridDim.x * 256)
        p[i] = atomicAdd(off + idx[i], 1u);
}

// ================= msg kernel: fused MLP -> msg[pos[m]] =================
// R14 restructure: 8 waves = 4 rowgroups (32 atoms) x 2 col-halves.
// Each B-fragment ds_read_b128 feeds TWO MFMAs (row frags) -> GEMM LDS
// B-read traffic halved vs 16-row waves. W2 prefetched into registers at
// kernel start so stage-2 is a pure LDS write (no exposed L2 round-trip).
template<int A>
__global__ __launch_bounds__(512) void msg_kernel(
    const u16* __restrict__ nsb, const int* __restrict__ idx,
    const u32* __restrict__ pos,
    const u16* __restrict__ w1T, const float* __restrict__ b1,
    const u16* __restrict__ w2T, const float* __restrict__ b2,
    u16* __restrict__ msg, int T)
{
    constexpr int D   = A * 64;
    constexpr int KS  = D / 32;          // k-steps of 32
    constexpr int NT  = D / 16;          // total 16-col tiles
    constexpr int NT2 = NT / 2;          // col tiles per wave (half of D)
    constexpr int NW2 = D * D / 8 / 512; // uint4 per thread for W2 prefetch
    __shared__ __align__(16) u16 Wl[D * D];
    __shared__ __align__(16) u16 h1[128 * D];    // H1, later reused as msg staging

    const int tid  = threadIdx.x;
    const int lane = tid & 63;
    const int w    = tid >> 6;
    const int g    = lane >> 4;
    const int lr   = lane & 15;
    const int rg   = w >> 1;             // row group: atoms rg*32 .. rg*32+31
    const int cg   = w & 1;              // column half

    const int tile = blockIdx.x * 128;

    // W2 -> registers (latency hidden under gather + W1 stage + GEMM1)
    uint4 w2r[NW2];
    {
        const uint4* s4 = (const uint4*)w2T;
#pragma unroll
        for (int i = 0; i < NW2; ++i) w2r[i] = s4[i * 512 + tid];
    }

    // stage W1 (global copy is pre-swizzled; linear copy)
    {
        constexpr int NV = D * D / 8;
        const uint4* s4 = (const uint4*)w1T;
        uint4* d4 = (uint4*)Wl;
#pragma unroll
        for (int i = 0; i < NV / 512; ++i) d4[i * 512 + tid] = s4[i * 512 + tid];
    }

    // gather A fragments for this wave's 32 atom rows (2 row frags)
    bf16x8 a1[2][KS];
#pragma unroll
    for (int rf = 0; rf < 2; ++rf) {
        const int trow = tile + rg * 32 + rf * 16 + lr;
        const int tl   = trow < T ? trow : T - 1;
        int nodes[A];
#pragma unroll
        for (int s = 0; s < A; ++s) nodes[s] = idx[(long)tl * A + s];
#pragma unroll
        for (int kk = 0; kk < KS; ++kk) {
            const u16* p = nsb + (long)nodes[kk >> 1] * H + ((kk & 1) * 32 + g * 8);
            F8 t; t.q = *(const uint4*)p;
            a1[rf][kk] = t.b;
        }
    }

    float bias1[NT2], bias2[NT2];
#pragma unroll
    for (int j = 0; j < NT2; ++j) bias1[j] = b1[(cg * NT2 + j) * 16 + lr];
#pragma unroll
    for (int j = 0; j < NT2; ++j) bias2[j] = b2[(cg * NT2 + j) * 16 + lr];

    __syncthreads();                               // W1 resident

    // GEMM1: 32 rows x NT2 col-tiles per wave; B reused for both row frags
#pragma unroll
    for (int j = 0; j < NT2; ++j) {
        const int jg = cg * NT2 + j;
        f32x4 acc0 = {0.f, 0.f, 0.f, 0.f};
        f32x4 acc1 = {0.f, 0.f, 0.f, 0.f};
#pragma unroll
        for (int kk = 0; kk < KS; ++kk) {
            F8 bf; bf.q = *(const uint4*)((const char*)Wl + swz(jg * 16 + lr, kk * 32 + g * 8, D));
            acc0 = __builtin_amdgcn_mfma_f32_16x16x32_bf16(a1[0][kk], bf.b, acc0, 0, 0, 0);
            acc1 = __builtin_amdgcn_mfma_f32_16x16x32_bf16(a1[1][kk], bf.b, acc1, 0, 0, 0);
        }
#pragma unroll
        for (int r = 0; r < 4; ++r) {
            float v0 = acc0[r] + bias1[j]; v0 = v0 > 0.f ? v0 : 0.f;
            float v1 = acc1[r] + bias1[j]; v1 = v1 > 0.f ? v1 : 0.f;
            const int row0 = rg * 32 + g * 4 + r;
            *(u16*)((char*)h1 + swz(row0,      jg * 16 + lr, D)) = f2bf(v0);
            *(u16*)((char*)h1 + swz(row0 + 16, jg * 16 + lr, D)) = f2bf(v1);
        }
    }

    __syncthreads();                               // h1 complete, W1 reads done

    // W2 registers -> LDS (no global wait here)
    {
        uint4* d4 = (uint4*)Wl;
#pragma unroll
        for (int i = 0; i < NW2; ++i) d4[i * 512 + tid] = w2r[i];
    }

    // a2 fragments: wave's 32 h1 rows, full D k-range
    bf16x8 a2[2][KS];
#pragma unroll
    for (int rf = 0; rf < 2; ++rf) {
        const int row = rg * 32 + rf * 16 + lr;
#pragma unroll
        for (int kk = 0; kk < KS; ++kk) {
            F8 t; t.q = *(const uint4*)((const char*)h1 + swz(row, kk * 32 + g * 8, D));
            a2[rf][kk] = t.b;
        }
    }

    __syncthreads();                               // W2 resident, all a2 reads done

    // GEMM2 -> stage message rows into h1 ([mrow][64] swizzled)
#pragma unroll
    for (int j = 0; j < NT2; ++j) {
        const int jg = cg * NT2 + j;
        f32x4 acc0 = {0.f, 0.f, 0.f, 0.f};
        f32x4 acc1 = {0.f, 0.f, 0.f, 0.f};
#pragma unroll
        for (int kk = 0; kk < KS; ++kk) {
            F8 bf; bf.q = *(const uint4*)((const char*)Wl + swz(jg * 16 + lr, kk * 32 + g * 8, D));
            acc0 = __builtin_amdgcn_mfma_f32_16x16x32_bf16(a2[0][kk], bf.b, acc0, 0, 0, 0);
            acc1 = __builtin_amdgcn_mfma_f32_16x16x32_bf16(a2[1][kk], bf.b, acc1, 0, 0, 0);
        }
        const int gc   = jg * 16 + lr;             // global output col in D
        const int slot = gc >> 6;                  // which 64-col message slot
        const int cs   = gc & 63;
#pragma unroll
        for (int r = 0; r < 4; ++r) {
            const int a0 = rg * 32 + g * 4 + r;    // local atom (row frag 0)
            const int m0 = a0 * A + slot;
            const int m1 = (a0 + 16) * A + slot;
            *(u16*)((char*)h1 + ((((unsigned)(m0 * 64 + cs)) * 2u) ^ (((unsigned)m0 & 7u) << 4))) = f2bf(acc0[r] + bias2[j]);
            *(u16*)((char*)h1 + ((((unsigned)(m1 * 64 + cs)) * 2u) ^ (((unsigned)m1 & 7u) << 4))) = f2bf(acc1[r] + bias2[j]);
        }
    }

    __syncthreads();                               // staged msg complete

    // stream staged rows to sorted positions (block-wide; pos lookup only)
    const int mbase = tile * A;                    // relation-local message id base
    constexpr int CH = 128 * A * 16;               // total uint2 chunks
#pragma unroll
    for (int i = 0; i < CH / 512; ++i) {
        const int c    = i * 512 + tid;
        const int row  = c >> 4;                   // local message row
        const int atom = row / A;
        if (tile + atom < T) {
            u32 p = pos[mbase + row];
            unsigned byte = (((unsigned)(row * 64 + (c & 15) * 4)) * 2u) ^ (((unsigned)row & 7u) << 4);
            uint2 v = *(const uint2*)((const char*)h1 + byte);
            *(uint2*)(msg + (size_t)p * 64 + (c & 15) * 4) = v;
        }
    }
}

// ================= fallback: fused with f32 atomics into d_out =================
template<int A, bool NSB>
__global__ __launch_bounds__(512) void rel_kernel(
    const float* __restrict__ ns, const u16* __restrict__ nsb,
    const int* __restrict__ idx,
    const u16* __restrict__ w1T, const float* __restrict__ b1,
    const u16* __restrict__ w2T, const float* __restrict__ b2,
    float* __restrict__ dout, int T)
{
    constexpr int D  = A * 64;
    constexpr int KS = D / 32;
    constexpr int NT = D / 16;
    constexpr bool DUAL = (A == 1);
    __shared__ __align__(16) u16 Wl[(DUAL ? 2 : 1) * D * D];
    __shared__ __align__(16) u16 h1[128 * D];

    const int tid  = threadIdx.x;
    const int lane = tid & 63;
    const int w    = tid >> 6;
    const int g    = lane >> 4;
    const int lr   = lane & 15;

    const int tile = blockIdx.x * 128;
    const int trow = tile + w * 16 + lr;
    const int tl   = trow < T ? trow : T - 1;

    {
        constexpr int NV = (DUAL ? 2 : 1) * D * D / 8;
        const uint4* s4 = (const uint4*)w1T;
        uint4* d4 = (uint4*)Wl;
#pragma unroll
        for (int i = 0; i < NV / 512; ++i) d4[i * 512 + tid] = s4[i * 512 + tid];
    }

    int nodes[A];
#pragma unroll
    for (int s = 0; s < A; ++s) nodes[s] = idx[(long)tl * A + s];

    bf16x8 a1[KS];
#pragma unroll
    for (int kk = 0; kk < KS; ++kk) {
        if constexpr (NSB) {
            const u16* p = nsb + (long)nodes[kk >> 1] * H + ((kk & 1) * 32 + g * 8);
            F8 t; t.q = *(const uint4*)p;
            a1[kk] = t.b;
        } else {
            const float* p = ns + (long)nodes[kk >> 1] * H + ((kk & 1) * 32 + g * 8);
            float4 f0 = *(const float4*)p;
            float4 f1 = *(const float4*)(p + 4);
            F8 t;
            t.u[0] = f2bf(f0.x); t.u[1] = f2bf(f0.y); t.u[2] = f2bf(f0.z); t.u[3] = f2bf(f0.w);
            t.u[4] = f2bf(f1.x); t.u[5] = f2bf(f1.y); t.u[6] = f2bf(f1.z); t.u[7] = f2bf(f1.w);
            a1[kk] = t.b;
        }
    }

    float bias1[NT];
#pragma unroll
    for (int j = 0; j < NT; ++j) bias1[j] = b1[j * 16 + lr];

    __syncthreads();

#pragma unroll
    for (int j = 0; j < NT; ++j) {
        f32x4 acc = {0.f, 0.f, 0.f, 0.f};
#pragma unroll
        for (int kk = 0; kk < KS; ++kk) {
            F8 bf; bf.q = *(const uint4*)((const char*)Wl + swz(j * 16 + lr, kk * 32 + g * 8, D));
            acc = __builtin_amdgcn_mfma_f32_16x16x32_bf16(a1[kk], bf.b, acc, 0, 0, 0);
        }
#pragma unroll
        for (int r = 0; r < 4; ++r) {
            float vv = acc[r] + bias1[j];
            vv = vv > 0.f ? vv : 0.f;
            int row = w * 16 + g * 4 + r;
            *(u16*)((char*)h1 + swz(row, j * 16 + lr, D)) = f2bf(vv);
        }
    }

    const char* W2base;
    if constexpr (!DUAL) {
        __syncthreads();
        const uint4* s4 = (const uint4*)w2T;
        uint4* d4 = (uint4*)Wl;
        constexpr int NV = D * D / 8;
#pragma unroll
        for (int i = 0; i < NV / 512; ++i) d4[i * 512 + tid] = s4[i * 512 + tid];
        W2base = (const char*)Wl;
    } else {
        W2base = (const char*)(Wl + D * D);
    }

    bf16x8 a2[KS];
#pragma unroll
    for (int kk = 0; kk < KS; ++kk) {
        int row = w * 16 + lr;
        F8 t; t.q = *(const uint4*)((const char*)h1 + swz(row, kk * 32 + g * 8, D));
        a2[kk] = t.b;
    }

    float bias2[NT];
#pragma unroll
    for (int j = 0; j < NT; ++j) bias2[j] = b2[j * 16 + lr];

    int  nodes2[A][4];
    bool pred[4];
#pragma unroll
    for (int r = 0; r < 4; ++r) {
        int t  = tile + w * 16 + g * 4 + r;
        int tc = t < T ? t : T - 1;
        pred[r] = t < T;
#pragma unroll
        for (int s = 0; s < A; ++s) nodes2[s][r] = idx[(long)tc * A + s];
    }
    if constexpr (!DUAL) __syncthreads();

#pragma unroll
    for (int j = 0; j < NT; ++j) {
        f32x4 acc = {0.f, 0.f, 0.f, 0.f};
#pragma unroll
        for (int kk = 0; kk < KS; ++kk) {
            F8 bf; bf.q = *(const uint4*)(W2base + swz(j * 16 + lr, kk * 32 + g * 8, D));
            acc = __builtin_amdgcn_mfma_f32_16x16x32_bf16(a2[kk], bf.b, acc, 0, 0, 0);
        }
        const int slot = j >> 2;
        const int coff = (j & 3) * 16 + lr;
#pragma unroll
        for (int r = 0; r < 4; ++r) {
            if (pred[r])
                unsafeAtomicAdd(dout + (long)nodes2[slot][r] * H + coff, acc[r] + bias2[j]);
        }
    }
}

// ---------------- update: fused segment-sum (SEG) + 2-layer MLP ----------------
template<bool SEG, bool NSB>
__global__ __launch_bounds__(512) void update_kernel(
    const float* __restrict__ ns, const u16* __restrict__ nsb,
    const float* __restrict__ sum,
    const u32* __restrict__ base, const u16* __restrict__ msg, int Mtot,
    const u16* __restrict__ wu1T, const float* __restrict__ bu1,
    const u16* __restrict__ wu2T, const float* __restrict__ bu2,
    float* __restrict__ out, int N)
{
    __shared__ __align__(16) u16 Wl[128 * 128 + 64 * 128];
    __shared__ __align__(16) u16 h[128 * 128];

    const int tid  = threadIdx.x;
    const int lane = tid & 63;
    const int w    = tid >> 6;
    const int g    = lane >> 4;
    const int lr   = lane & 15;

    {
        const uint4* s4 = (const uint4*)wu1T;
        uint4* d4 = (uint4*)Wl;
#pragma unroll
        for (int i = 0; i < 6; ++i) d4[i * 512 + tid] = s4[i * 512 + tid];
    }

    const int tile = blockIdx.x * 128;
    const int trow = tile + w * 16 + lr;
    const int tl   = trow < N ? trow : N - 1;

    bf16x8 a1[4];
    if constexpr (SEG) {
        const u32 s = base[tl];
        const u32 e = (tl + 1 < N) ? base[tl + 1] : (u32)Mtot;
        float s0[8], s1[8];
#pragma unroll
        for (int j = 0; j < 8; ++j) { s0[j] = 0.f; s1[j] = 0.f; }
        for (u32 p = s; p < e; ++p) {
            const u16* row = msg + (size_t)p * 64;
            F8 v0, v1;
            v0.q = *(const uint4*)(row + g * 8);
            v1.q = *(const uint4*)(row + 32 + g * 8);
#pragma unroll
            for (int j = 0; j < 8; ++j) { s0[j] += bf2f(v0.u[j]); s1[j] += bf2f(v1.u[j]); }
        }
        F8 t0, t1;
#pragma unroll
        for (int j = 0; j < 8; ++j) { t0.u[j] = f2bf(s0[j]); t1.u[j] = f2bf(s1[j]); }
        a1[0] = t0.b; a1[1] = t1.b;
    } else {
#pragma unroll
        for (int kk = 0; kk < 2; ++kk) {
            int k = kk * 32 + g * 8;
            const float* p = sum + (long)tl * H + k;
            float4 f0 = *(const float4*)p;
            float4 f1 = *(const float4*)(p + 4);
            F8 t;
            t.u[0] = f2bf(f0.x); t.u[1] = f2bf(f0.y); t.u[2] = f2bf(f0.z); t.u[3] = f2bf(f0.w);
            t.u[4] = f2bf(f1.x); t.u[5] = f2bf(f1.y); t.u[6] = f2bf(f1.z); t.u[7] = f2bf(f1.w);
            a1[kk] = t.b;
        }
    }
#pragma unroll
    for (int kk = 2; kk < 4; ++kk) {
        if (NSB) {
            const u16* prow = nsb + (long)tl * H;
            F8 t; t.q = *(const uint4*)(prow + (kk - 2) * 32 + g * 8);
            a1[kk] = t.b;
        } else {
            int k = (kk - 2) * 32 + g * 8;
            const float* p = ns + (long)tl * H + k;
            float4 f0 = *(const float4*)p;
            float4 f1 = *(const float4*)(p + 4);
            F8 t;
            t.u[0] = f2bf(f0.x); t.u[1] = f2bf(f0.y); t.u[2] = f2bf(f0.z); t.u[3] = f2bf(f0.w);
            t.u[4] = f2bf(f1.x); t.u[5] = f2bf(f1.y); t.u[6] = f2bf(f1.z); t.u[7] = f2bf(f1.w);
            a1[kk] = t.b;
        }
    }

    float bias1[8], bias2[4];
#pragma unroll
    for (int j = 0; j < 8; ++j) bias1[j] = bu1[j * 16 + lr];
#pragma unroll
    for (int j = 0; j < 4; ++j) bias2[j] = bu2[j * 16 + lr];

    __syncthreads();

#pragma unroll
    for (int j = 0; j < 8; ++j) {
        f32x4 acc = {0.f, 0.f, 0.f, 0.f};
#pragma unroll
        for (int kk = 0; kk < 4; ++kk) {
            F8 bf; bf.q = *(const uint4*)((const char*)Wl + swz(j * 16 + lr, kk * 32 + g * 8, 128));
            acc = __builtin_amdgcn_mfma_f32_16x16x32_bf16(a1[kk], bf.b, acc, 0, 0, 0);
        }
#pragma unroll
        for (int r = 0; r < 4; ++r) {
            float vv = acc[r] + bias1[j];
            vv = vv > 0.f ? vv : 0.f;
            int row = w * 16 + g * 4 + r;
            *(u16*)((char*)h + swz(row, j * 16 + lr, 128)) = f2bf(vv);
        }
    }

    bf16x8 a2[4];
#pragma unroll
    for (int kk = 0; kk < 4; ++kk) {
        int row = w * 16 + lr;
        F8 t; t.q = *(const uint4*)((const char*)h + swz(row, kk * 32 + g * 8, 128));
        a2[kk] = t.b;
    }

    const char* W2base = (const char*)(Wl + 128 * 128);
#pragma unroll
    for (int j = 0; j < 4; ++j) {
        f32x4 acc = {0.f, 0.f, 0.f, 0.f};
#pragma unroll
        for (int kk = 0; kk < 4; ++kk) {
            F8 bf; bf.q = *(const uint4*)(W2base + swz(j * 16 + lr, kk * 32 + g * 8, 128));
            acc = __builtin_amdgcn_mfma_f32_16x16x32_bf16(a2[kk], bf.b, acc, 0, 0, 0);
        }
#pragma unroll
        for (int r = 0; r < 4; ++r) {
            int t = tile + w * 16 + g * 4 + r;
            if (t < N) out[(long)t * H + j * 16 + lr] = acc[r] + bias2[j];
        }
    }
}

// ---------------- launcher ----------------
extern "C" void kernel_launch(void* const* d_in, const int* in_sizes, int n_in,
                              void* d_out, int out_size, void* d_ws, size_t ws_size,
                              hipStream_t stream) {
    const float* ns = (const float*)d_in[0];
    const int* idxs[3] = { (const int*)d_in[1], (const int*)d_in[6], (const int*)d_in[11] };
    const float* b1s[3] = { (const float*)d_in[3], (const float*)d_in[8], (const float*)d_in[13] };
    const float* b2s[3] = { (const float*)d_in[5], (const float*)d_in[10], (const float*)d_in[15] };
    const float* bu1 = (const float*)d_in[17];
    const float* bu2 = (const float*)d_in[19];

    const int N = in_sizes[0] / H;
    const int Ts[3] = { in_sizes[1], in_sizes[6] / 2, in_sizes[11] / 3 };
    const int Ms[3] = { Ts[0] * 1, Ts[1] * 2, Ts[2] * 3 };
    const long Mtot = (long)Ms[0] + Ms[1] + Ms[2];

    char* wsb = (char*)d_ws;
    auto AL = [](size_t x) { return (x + 255) & ~(size_t)255; };

    const unsigned O_W1R0 = 0;
    const unsigned O_W2R0 = O_W1R0 + 64 * 64 * 2;
    const unsigned O_W1R1 = O_W2R0 + 64 * 64 * 2;
    const unsigned O_W2R1 = O_W1R1 + 128 * 128 * 2;
    const unsigned O_W1R2 = O_W2R1 + 128 * 128 * 2;
    const unsigned O_W2R2 = O_W1R2 + 192 * 192 * 2;
    const unsigned O_WU1  = O_W2R2 + 192 * 192 * 2;
    const unsigned O_WU2  = O_WU1 + 128 * 128 * 2;
    const size_t  wEnd    = O_WU2 + 128 * 64 * 2;
    const unsigned wOff1[3] = { O_W1R0, O_W1R1, O_W1R2 };
    const unsigned wOff2[3] = { O_W2R0, O_W2R1, O_W2R2 };

    const int nb = (N + 511) / 512;

    const size_t O_CNT = AL(wEnd);                       // becomes base after scan
    const size_t O_OFF = AL(O_CNT + (size_t)N * 4);      // rank cursor
    const size_t O_SUM = AL(O_OFF + (size_t)N * 4);
    const size_t O_POS = AL(O_SUM + (size_t)nb * 4);
    const size_t O_NSB = AL(O_POS + (size_t)Mtot * 4);
    const size_t nsLen = (size_t)N * H * 2;
    const size_t O_MSG = AL(O_NSB + nsLen);
    const size_t need  = O_MSG + (size_t)Mtot * 128;

    const bool sorted = (nb <= 512) && (ws_size >= need);
    const bool nsbOk  = ws_size >= O_NSB + nsLen;

    Segs segs;
    segs.s[0] = {(const float*)d_in[2],  O_W1R0, 64, 64};
    segs.s[1] = {(const float*)d_in[4],  O_W2R0, 64, 64};
    segs.s[2] = {(const float*)d_in[7],  O_W1R1, 128, 128};
    segs.s[3] = {(const float*)d_in[9],  O_W2R1, 128, 128};
    segs.s[4] = {(const float*)d_in[12], O_W1R2, 192, 192};
    segs.s[5] = {(const float*)d_in[14], O_W2R2, 192, 192};
    segs.s[6] = {(const float*)d_in[16], O_WU1, 128, 128};
    segs.s[7] = {(const float*)d_in[18], O_WU2, 128, 64};

    conv_weights<<<dim3(36, 8), 256, 0, stream>>>(segs, wsb);

    float* dout = (float*)d_out;
    u16* nsbp = (u16*)(wsb + O_NSB);

    const u16* W1[3] = { (const u16*)(wsb + wOff1[0]), (const u16*)(wsb + wOff1[1]), (const u16*)(wsb + wOff1[2]) };
    const u16* W2[3] = { (const u16*)(wsb + wOff2[0]), (const u16*)(wsb + wOff2[1]), (const u16*)(wsb + wOff2[2]) };

    auto gT = [](int T) { return (T + 127) / 128; };

    if (sorted) {
        u32* cnt = (u32*)(wsb + O_CNT);   // exclusive base after scan
        u32* off = (u32*)(wsb + O_OFF);
        u32* sums = (u32*)(wsb + O_SUM);
        u32* pos = (u32*)(wsb + O_POS);
        u16* msg = (u16*)(wsb + O_MSG);

        I3 h3; for (int r = 0; r < 3; ++r) { h3.idx[r] = idxs[r]; h3.m[r] = Ms[r]; }

        hipMemsetAsync(cnt, 0, (size_t)N * 4, stream);
        CNH cnh; cnh.src = (const float4*)ns; cnh.dst = (ushort4*)nsbp;
        cnh.n4 = N * H / 4; cnh.h = h3; cnh.cnt = cnt;
        conv_nodes_hist<<<dim3(512, 4), 256, 0, stream>>>(cnh);

        scan_blocks<<<nb, 512, 0, stream>>>(cnt, sums, N);
        scan_sums<<<1, 512, 0, stream>>>(sums, nb);
        scan_add2<<<nb, 512, 0, stream>>>(cnt, off, sums, N);
        rank_all<<<dim3(512, 3), 256, 0, stream>>>(h3, off, pos);

        msg_kernel<1><<<gT(Ts[0]), 512, 0, stream>>>(
            nsbp, idxs[0], pos, W1[0], b1s[0], W2[0], b2s[0], msg, Ts[0]);
        msg_kernel<2><<<gT(Ts[1]), 512, 0, stream>>>(
            nsbp, idxs[1], pos + Ms[0], W1[1], b1s[1], W2[1], b2s[1], msg, Ts[1]);
        msg_kernel<3><<<gT(Ts[2]), 512, 0, stream>>>(
            nsbp, idxs[2], pos + Ms[0] + Ms[1], W1[2], b1s[2], W2[2], b2s[2], msg, Ts[2]);

        update_kernel<true, true><<<(N + 127) / 128, 512, 0, stream>>>(
            ns, nsbp, nullptr, cnt, msg, (int)Mtot,
            (const u16*)(wsb + O_WU1), bu1, (const u16*)(wsb + O_WU2), bu2, dout, N);
    } else {
        if (nsbOk) {
            CNH cnh; cnh.src = (const float4*)ns; cnh.dst = (ushort4*)nsbp;
            cnh.n4 = N * H / 4;
            for (int r = 0; r < 3; ++r) { cnh.h.idx[r] = idxs[0]; cnh.h.m[r] = 0; }
            cnh.cnt = (u32*)(wsb + O_CNT);
            conv_nodes_hist<<<dim3(512, 1), 256, 0, stream>>>(cnh);
        }
        hipMemsetAsync(dout, 0, (size_t)N * H * sizeof(float), stream);
        for (int r = 0; r < 3; ++r) {
            const int T = Ts[r], nbl = gT(T);
            if (nsbOk) {
                if (r == 0) rel_kernel<1, true><<<nbl, 512, 0, stream>>>(ns, nsbp, idxs[0], W1[0], b1s[0], W2[0], b2s[0], dout, T);
                if (r == 1) rel_kernel<2, true><<<nbl, 512, 0, stream>>>(ns, nsbp, idxs[1], W1[1], b1s[1], W2[1], b2s[1], dout, T);
                if (r == 2) rel_kernel<3, true><<<nbl, 512, 0, stream>>>(ns, nsbp, idxs[2], W1[2], b1s[2], W2[2], b2s[2], dout, T);
            } else {
                if (r == 0) rel_kernel<1, false><<<nbl, 512, 0, stream>>>(ns, nullptr, idxs[0], W1[0], b1s[0], W2[0], b2s[0], dout, T);
                if (r == 1) rel_kernel<2, false><<<nbl, 512, 0, stream>>>(ns, nullptr, idxs[1], W1[1], b1s[1], W2[1], b2s[1], dout, T);
                if (r == 2) rel_kernel<3, false><<<nbl, 512, 0, stream>>>(ns, nullptr, idxs[2], W1[2], b1s[2], W2[2], b2s[2], dout, T);
            }
        }
        if (nsbOk)
            update_kernel<false, true><<<(N + 127) / 128, 512, 0, stream>>>(
                ns, nsbp, dout, nullptr, nullptr, 0,
                (const u16*)(wsb + O_WU1), bu1, (const u16*)(wsb + O_WU2), bu2, dout, N);
        else
            update_kernel<false, false><<<(N + 127) / 128, 512, 0, stream>>>(
                ns, nullptr, dout, nullptr, nullptr, 0,
                (const u16*)(wsb + O_WU1), bu1, (const u16*)(wsb + O_WU2), bu2, dout, N);
    }
}

// Round 2
// 366.670 us; speedup vs baseline: 1.1937x; 1.1937x over previous
//
#include <hip/hip_runtime.h>

#define H 64

typedef __attribute__((ext_vector_type(8))) __bf16 bf16x8;
typedef __attribute__((ext_vector_type(4))) float f32x4;
typedef unsigned short u16;
typedef unsigned int u32;

union F8 { bf16x8 b; u16 u[8]; uint4 q; };

__device__ __forceinline__ u16 f2bf(float f) {
    union { float f; u32 u; } v; v.f = f;
    u32 r = v.u + 0x7FFF + ((v.u >> 16) & 1);   // RNE
    return (u16)(r >> 16);
}
__device__ __forceinline__ float bf2f(u16 x) {
    return __uint_as_float((u32)x << 16);
}
// Swizzled layout: element (col,k) at byte ((col*K+k)*2) ^ ((col&7)<<4).
__device__ __forceinline__ unsigned swz(int col, int k, int K) {
    return ((unsigned)(col * K + k) * 2u) ^ (((unsigned)col & 7u) << 4);
}

// ---------------- weight convert ----------------
struct Seg { const float* src; unsigned dstBytes; int K; int N; };
struct Segs { Seg s[8]; };

__global__ __launch_bounds__(256) void conv_weights(Segs segs, char* out) {
    Seg sg = segs.s[blockIdx.y];
    int total = sg.K * sg.N;
    char* dst = out + sg.dstBytes;
    for (int e = blockIdx.x * 256 + threadIdx.x; e < total; e += gridDim.x * 256) {
        int k = e / sg.N, n = e % sg.N;
        *(u16*)(dst + swz(n, k, sg.K)) = f2bf(sg.src[e]);
    }
}

// ---------------- fused: node f32->bf16 convert + destination histogram ----------------
struct I3 { const int* idx[3]; int m[3]; };
struct CNH { const float4* src; ushort4* dst; int n4; I3 h; u32* cnt; };

__global__ __launch_bounds__(256) void conv_nodes_hist(CNH a) {
    if (blockIdx.y == 0) {
        for (int i = blockIdx.x * 256 + threadIdx.x; i < a.n4; i += gridDim.x * 256) {
            float4 f = a.src[i];
            ushort4 o;
            o.x = f2bf(f.x); o.y = f2bf(f.y); o.z = f2bf(f.z); o.w = f2bf(f.w);
            a.dst[i] = o;
        }
    } else {
        const int r = blockIdx.y - 1;
        const int* idx = a.h.idx[r];
        const int M = a.h.m[r];
        for (int i = blockIdx.x * 256 + threadIdx.x; i < M; i += gridDim.x * 256)
            atomicAdd(a.cnt + idx[i], 1u);
    }
}

// ---------------- scan (3 kernels); scan_add2 emits base AND the rank cursor ----------------
__global__ __launch_bounds__(512) void scan_blocks(u32* __restrict__ data,
                                                   u32* __restrict__ sums, int n) {
    __shared__ u32 s[512];
    int tid = threadIdx.x, i = blockIdx.x * 512 + tid;
    u32 v = (i < n) ? data[i] : 0u;
    s[tid] = v; __syncthreads();
    for (int d = 1; d < 512; d <<= 1) {
        u32 t = (tid >= d) ? s[tid - d] : 0u; __syncthreads();
        s[tid] += t; __syncthreads();
    }
    if (i < n) data[i] = s[tid] - v;               // exclusive
    if (tid == 511) sums[blockIdx.x] = s[511];
}

__global__ __launch_bounds__(512) void scan_sums(u32* __restrict__ sums, int nb) {
    __shared__ u32 s[512];
    int tid = threadIdx.x;
    u32 v = (tid < nb) ? sums[tid] : 0u;
    s[tid] = v; __syncthreads();
    for (int d = 1; d < 512; d <<= 1) {
        u32 t = (tid >= d) ? s[tid - d] : 0u; __syncthreads();
        s[tid] += t; __syncthreads();
    }
    if (tid < nb) sums[tid] = s[tid] - v;          // exclusive
}

__global__ __launch_bounds__(512) void scan_add2(u32* __restrict__ data,
                                                 u32* __restrict__ off,
                                                 const u32* __restrict__ sums, int n) {
    int i = blockIdx.x * 512 + threadIdx.x;
    if (i < n) { u32 v = data[i] + sums[blockIdx.x]; data[i] = v; off[i] = v; }
}

// pos[segOff + i] = sorted slot of message i of relation blockIdx.y
__global__ __launch_bounds__(256) void rank_all(I3 h, u32* __restrict__ off,
                                                u32* __restrict__ pos) {
    const int r = blockIdx.y;
    const int* idx = h.idx[r];
    const int M = h.m[r];
    u32* p = pos;
    for (int q = 0; q < r; ++q) p += h.m[q];
    for (int i = blockIdx.x * 256 + threadIdx.x; i < M; i += gridDim.x * 256)
        p[i] = atomicAdd(off + idx[i], 1u);
}

// ================= msg kernel: fused MLP -> msg[pos[m]] =================
// R15: 8 waves x 32 atoms (2 row-fragments) x FULL cols = 256-atom blocks.
// Each W ds_read_b128 feeds 2 MFMAs -> per-atom LDS B-read traffic halves
// vs R13, with NO gather duplication (each wave owns distinct atoms).
// A=3: W staged in column-halves (Wbuf 36KB, h1 96KB, total 132KB LDS).
// A=1: DUAL (W1+W2 staged upfront, 49KB -> 3 blocks/CU, 1 barrier).
// Own-wave region identity: wave w's H1 rows [w*32,(w+1)*32) x D*2B ==
// its msg-staging rows [w*32*A,(w+1)*32*A) x 128B, so GEMM2 staging and
// stream-out need no extra barriers. __launch_bounds__(512,2): LDS caps
// at 1 block/CU anyway, so allow up to 256 VGPR (R14's spill lesson).
template<int A>
__global__ __launch_bounds__(512, 2) void msg_kernel(
    const u16* __restrict__ nsb, const int* __restrict__ idx,
    const u32* __restrict__ pos,
    const u16* __restrict__ w1T, const float* __restrict__ b1,
    const u16* __restrict__ w2T, const float* __restrict__ b2,
    u16* __restrict__ msg, int T)
{
    constexpr int D    = A * 64;
    constexpr int KS   = D / 32;           // k-steps of 32
    constexpr int NT   = D / 16;           // 16-col tiles (full)
    constexpr int WH   = (A == 3) ? 2 : 1; // W staged in column halves?
    constexpr int NTH  = NT / WH;          // col tiles per half
    constexpr int COLH = D / WH;           // cols per half
    constexpr bool DUAL = (A == 1);        // W1+W2 staged upfront
    __shared__ __align__(16) u16 Wl[DUAL ? 2 * D * D : COLH * D];
    __shared__ __align__(16) u16 h1[256 * D];   // H1, later reused as msg staging

    const int tid  = threadIdx.x;
    const int lane = tid & 63;
    const int w    = tid >> 6;
    const int g    = lane >> 4;
    const int lr   = lane & 15;

    const int tile = blockIdx.x * 256;

    // gather A fragments: wave owns atoms [w*32, w*32+32)
    bf16x8 a1[2][KS];
#pragma unroll
    for (int rf = 0; rf < 2; ++rf) {
        const int trow = tile + w * 32 + rf * 16 + lr;
        const int tl   = trow < T ? trow : T - 1;
        int nodes[A];
#pragma unroll
        for (int s = 0; s < A; ++s) nodes[s] = idx[(long)tl * A + s];
#pragma unroll
        for (int kk = 0; kk < KS; ++kk) {
            const u16* p = nsb + (long)nodes[kk >> 1] * H + ((kk & 1) * 32 + g * 8);
            F8 t; t.q = *(const uint4*)p;
            a1[rf][kk] = t.b;
        }
    }

    float bias1[NT], bias2[NT];
#pragma unroll
    for (int j = 0; j < NT; ++j) bias1[j] = b1[j * 16 + lr];
#pragma unroll
    for (int j = 0; j < NT; ++j) bias2[j] = b2[j * 16 + lr];

    // ---- GEMM1 (over W column-halves) ----
#pragma unroll
    for (int hh = 0; hh < WH; ++hh) {
        if constexpr (DUAL) {
            // stage W1+W2 together (adjacent in workspace)
            const uint4* s4 = (const uint4*)w1T;
            uint4* d4 = (uint4*)Wl;
#pragma unroll
            for (int i = 0; i < 2 * D * D / 8 / 512; ++i) d4[i * 512 + tid] = s4[i * 512 + tid];
        } else if constexpr (WH == 2) {
            const uint2* s2 = (const uint2*)(w1T + (size_t)hh * COLH * D);
            uint2* d2 = (uint2*)Wl;
#pragma unroll
            for (int i = 0; i < COLH * D / 4 / 512; ++i) d2[i * 512 + tid] = s2[i * 512 + tid];
        } else {
            const uint4* s4 = (const uint4*)w1T;
            uint4* d4 = (uint4*)Wl;
#pragma unroll
            for (int i = 0; i < D * D / 8 / 512; ++i) d4[i * 512 + tid] = s4[i * 512 + tid];
        }
        __syncthreads();                           // W half resident

#pragma unroll
        for (int j = 0; j < NTH; ++j) {
            const int jg = hh * NTH + j;
            f32x4 acc0 = {0.f, 0.f, 0.f, 0.f};
            f32x4 acc1 = {0.f, 0.f, 0.f, 0.f};
#pragma unroll
            for (int kk = 0; kk < KS; ++kk) {
                F8 bf; bf.q = *(const uint4*)((const char*)Wl + swz(j * 16 + lr, kk * 32 + g * 8, D));
                acc0 = __builtin_amdgcn_mfma_f32_16x16x32_bf16(a1[0][kk], bf.b, acc0, 0, 0, 0);
                acc1 = __builtin_amdgcn_mfma_f32_16x16x32_bf16(a1[1][kk], bf.b, acc1, 0, 0, 0);
            }
#pragma unroll
            for (int r = 0; r < 4; ++r) {
                float v0 = acc0[r] + bias1[jg]; v0 = v0 > 0.f ? v0 : 0.f;
                float v1 = acc1[r] + bias1[jg]; v1 = v1 > 0.f ? v1 : 0.f;
                const int row0 = w * 32 + g * 4 + r;
                *(u16*)((char*)h1 + swz(row0,      jg * 16 + lr, D)) = f2bf(v0);
                *(u16*)((char*)h1 + swz(row0 + 16, jg * 16 + lr, D)) = f2bf(v1);
            }
        }
        if constexpr (!DUAL) __syncthreads();      // W reads done (before overwrite)
    }

    // a2 fragments: own-wave h1 rows (same-wave data; lgkmcnt ordering suffices)
    bf16x8 a2[2][KS];
#pragma unroll
    for (int rf = 0; rf < 2; ++rf) {
        const int row = w * 32 + rf * 16 + lr;
#pragma unroll
        for (int kk = 0; kk < KS; ++kk) {
            F8 t; t.q = *(const uint4*)((const char*)h1 + swz(row, kk * 32 + g * 8, D));
            a2[rf][kk] = t.b;
        }
    }

    // ---- GEMM2 (over W column-halves) -> stage msg rows into h1 region ----
#pragma unroll
    for (int hh = 0; hh < WH; ++hh) {
        if constexpr (!DUAL) {
            if constexpr (WH == 2) {
                const uint2* s2 = (const uint2*)(w2T + (size_t)hh * COLH * D);
                uint2* d2 = (uint2*)Wl;
#pragma unroll
                for (int i = 0; i < COLH * D / 4 / 512; ++i) d2[i * 512 + tid] = s2[i * 512 + tid];
            } else {
                const uint4* s4 = (const uint4*)w2T;
                uint4* d4 = (uint4*)Wl;
#pragma unroll
                for (int i = 0; i < D * D / 8 / 512; ++i) d4[i * 512 + tid] = s4[i * 512 + tid];
            }
            __syncthreads();                       // W2 half resident
        }
        const char* W2base = DUAL ? (const char*)(Wl + D * D) : (const char*)Wl;

#pragma unroll
        for (int j = 0; j < NTH; ++j) {
            const int jg = hh * NTH + j;
            f32x4 acc0 = {0.f, 0.f, 0.f, 0.f};
            f32x4 acc1 = {0.f, 0.f, 0.f, 0.f};
#pragma unroll
            for (int kk = 0; kk < KS; ++kk) {
                F8 bf; bf.q = *(const uint4*)(W2base + swz(j * 16 + lr, kk * 32 + g * 8, D));
                acc0 = __builtin_amdgcn_mfma_f32_16x16x32_bf16(a2[0][kk], bf.b, acc0, 0, 0, 0);
                acc1 = __builtin_amdgcn_mfma_f32_16x16x32_bf16(a2[1][kk], bf.b, acc1, 0, 0, 0);
            }
            const int gc   = jg * 16 + lr;         // global output col in D
            const int slot = gc >> 6;              // 64-col message slot
            const int cs   = gc & 63;
#pragma unroll
            for (int r = 0; r < 4; ++r) {
                const int a0 = w * 32 + g * 4 + r; // local atom (frag 0)
                const int m0 = a0 * A + slot;
                const int m1 = (a0 + 16) * A + slot;
                *(u16*)((char*)h1 + ((((unsigned)(m0 * 64 + cs)) * 2u) ^ (((unsigned)m0 & 7u) << 4))) = f2bf(acc0[r] + bias2[jg]);
                *(u16*)((char*)h1 + ((((unsigned)(m1 * 64 + cs)) * 2u) ^ (((unsigned)m1 & 7u) << 4))) = f2bf(acc1[r] + bias2[jg]);
            }
        }
        if constexpr (!DUAL) { if (hh + 1 < WH) __syncthreads(); }   // before Wl overwrite
    }

    // stream own-wave staged rows to sorted positions (no barrier needed:
    // staging region of wave w == its own h1 region)
    const int mbase = tile * A;
    const bool fullt = (tile + 256 <= T);
#pragma unroll
    for (int i = 0; i < 8 * A; ++i) {              // 32*A rows * 16 uint2 / 64 lanes
        const int c    = i * 64 + lane;
        const int row  = w * 32 * A + (c >> 4);
        const int atom = row / A;
        if (fullt || tile + atom < T) {
            u32 p = pos[mbase + row];
            unsigned byte = (((unsigned)(row * 64 + (c & 15) * 4)) * 2u) ^ (((unsigned)row & 7u) << 4);
            uint2 v = *(const uint2*)((const char*)h1 + byte);
            *(uint2*)(msg + (size_t)p * 64 + (c & 15) * 4) = v;
        }
    }
}

// ================= fallback: fused with f32 atomics into d_out =================
template<int A, bool NSB>
__global__ __launch_bounds__(512) void rel_kernel(
    const float* __restrict__ ns, const u16* __restrict__ nsb,
    const int* __restrict__ idx,
    const u16* __restrict__ w1T, const float* __restrict__ b1,
    const u16* __restrict__ w2T, const float* __restrict__ b2,
    float* __restrict__ dout, int T)
{
    constexpr int D  = A * 64;
    constexpr int KS = D / 32;
    constexpr int NT = D / 16;
    constexpr bool DUAL = (A == 1);
    __shared__ __align__(16) u16 Wl[(DUAL ? 2 : 1) * D * D];
    __shared__ __align__(16) u16 h1[128 * D];

    const int tid  = threadIdx.x;
    const int lane = tid & 63;
    const int w    = tid >> 6;
    const int g    = lane >> 4;
    const int lr   = lane & 15;

    const int tile = blockIdx.x * 128;
    const int trow = tile + w * 16 + lr;
    const int tl   = trow < T ? trow : T - 1;

    {
        constexpr int NV = (DUAL ? 2 : 1) * D * D / 8;
        const uint4* s4 = (const uint4*)w1T;
        uint4* d4 = (uint4*)Wl;
#pragma unroll
        for (int i = 0; i < NV / 512; ++i) d4[i * 512 + tid] = s4[i * 512 + tid];
    }

    int nodes[A];
#pragma unroll
    for (int s = 0; s < A; ++s) nodes[s] = idx[(long)tl * A + s];

    bf16x8 a1[KS];
#pragma unroll
    for (int kk = 0; kk < KS; ++kk) {
        if constexpr (NSB) {
            const u16* p = nsb + (long)nodes[kk >> 1] * H + ((kk & 1) * 32 + g * 8);
            F8 t; t.q = *(const uint4*)p;
            a1[kk] = t.b;
        } else {
            const float* p = ns + (long)nodes[kk >> 1] * H + ((kk & 1) * 32 + g * 8);
            float4 f0 = *(const float4*)p;
            float4 f1 = *(const float4*)(p + 4);
            F8 t;
            t.u[0] = f2bf(f0.x); t.u[1] = f2bf(f0.y); t.u[2] = f2bf(f0.z); t.u[3] = f2bf(f0.w);
            t.u[4] = f2bf(f1.x); t.u[5] = f2bf(f1.y); t.u[6] = f2bf(f1.z); t.u[7] = f2bf(f1.w);
            a1[kk] = t.b;
        }
    }

    float bias1[NT];
#pragma unroll
    for (int j = 0; j < NT; ++j) bias1[j] = b1[j * 16 + lr];

    __syncthreads();

#pragma unroll
    for (int j = 0; j < NT; ++j) {
        f32x4 acc = {0.f, 0.f, 0.f, 0.f};
#pragma unroll
        for (int kk = 0; kk < KS; ++kk) {
            F8 bf; bf.q = *(const uint4*)((const char*)Wl + swz(j * 16 + lr, kk * 32 + g * 8, D));
            acc = __builtin_amdgcn_mfma_f32_16x16x32_bf16(a1[kk], bf.b, acc, 0, 0, 0);
        }
#pragma unroll
        for (int r = 0; r < 4; ++r) {
            float vv = acc[r] + bias1[j];
            vv = vv > 0.f ? vv : 0.f;
            int row = w * 16 + g * 4 + r;
            *(u16*)((char*)h1 + swz(row, j * 16 + lr, D)) = f2bf(vv);
        }
    }

    const char* W2base;
    if constexpr (!DUAL) {
        __syncthreads();
        const uint4* s4 = (const uint4*)w2T;
        uint4* d4 = (uint4*)Wl;
        constexpr int NV = D * D / 8;
#pragma unroll
        for (int i = 0; i < NV / 512; ++i) d4[i * 512 + tid] = s4[i * 512 + tid];
        W2base = (const char*)Wl;
    } else {
        W2base = (const char*)(Wl + D * D);
    }

    bf16x8 a2[KS];
#pragma unroll
    for (int kk = 0; kk < KS; ++kk) {
        int row = w * 16 + lr;
        F8 t; t.q = *(const uint4*)((const char*)h1 + swz(row, kk * 32 + g * 8, D));
        a2[kk] = t.b;
    }

    float bias2[NT];
#pragma unroll
    for (int j = 0; j < NT; ++j) bias2[j] = b2[j * 16 + lr];

    int  nodes2[A][4];
    bool pred[4];
#pragma unroll
    for (int r = 0; r < 4; ++r) {
        int t  = tile + w * 16 + g * 4 + r;
        int tc = t < T ? t : T - 1;
        pred[r] = t < T;
#pragma unroll
        for (int s = 0; s < A; ++s) nodes2[s][r] = idx[(long)tc * A + s];
    }
    if constexpr (!DUAL) __syncthreads();

#pragma unroll
    for (int j = 0; j < NT; ++j) {
        f32x4 acc = {0.f, 0.f, 0.f, 0.f};
#pragma unroll
        for (int kk = 0; kk < KS; ++kk) {
            F8 bf; bf.q = *(const uint4*)(W2base + swz(j * 16 + lr, kk * 32 + g * 8, D));
            acc = __builtin_amdgcn_mfma_f32_16x16x32_bf16(a2[kk], bf.b, acc, 0, 0, 0);
        }
        const int slot = j >> 2;
        const int coff = (j & 3) * 16 + lr;
#pragma unroll
        for (int r = 0; r < 4; ++r) {
            if (pred[r])
                unsafeAtomicAdd(dout + (long)nodes2[slot][r] * H + coff, acc[r] + bias2[j]);
        }
    }
}

// ---------------- update: fused segment-sum (SEG) + 2-layer MLP ----------------
template<bool SEG, bool NSB>
__global__ __launch_bounds__(512) void update_kernel(
    const float* __restrict__ ns, const u16* __restrict__ nsb,
    const float* __restrict__ sum,
    const u32* __restrict__ base, const u16* __restrict__ msg, int Mtot,
    const u16* __restrict__ wu1T, const float* __restrict__ bu1,
    const u16* __restrict__ wu2T, const float* __restrict__ bu2,
    float* __restrict__ out, int N)
{
    __shared__ __align__(16) u16 Wl[128 * 128 + 64 * 128];
    __shared__ __align__(16) u16 h[128 * 128];

    const int tid  = threadIdx.x;
    const int lane = tid & 63;
    const int w    = tid >> 6;
    const int g    = lane >> 4;
    const int lr   = lane & 15;

    {
        const uint4* s4 = (const uint4*)wu1T;
        uint4* d4 = (uint4*)Wl;
#pragma unroll
        for (int i = 0; i < 6; ++i) d4[i * 512 + tid] = s4[i * 512 + tid];
    }

    const int tile = blockIdx.x * 128;
    const int trow = tile + w * 16 + lr;
    const int tl   = trow < N ? trow : N - 1;

    bf16x8 a1[4];
    if constexpr (SEG) {
        const u32 s = base[tl];
        const u32 e = (tl + 1 < N) ? base[tl + 1] : (u32)Mtot;
        float s0[8], s1[8];
#pragma unroll
        for (int j = 0; j < 8; ++j) { s0[j] = 0.f; s1[j] = 0.f; }
        for (u32 p = s; p < e; ++p) {
            const u16* row = msg + (size_t)p * 64;
            F8 v0, v1;
            v0.q = *(const uint4*)(row + g * 8);
            v1.q = *(const uint4*)(row + 32 + g * 8);
#pragma unroll
            for (int j = 0; j < 8; ++j) { s0[j] += bf2f(v0.u[j]); s1[j] += bf2f(v1.u[j]); }
        }
        F8 t0, t1;
#pragma unroll
        for (int j = 0; j < 8; ++j) { t0.u[j] = f2bf(s0[j]); t1.u[j] = f2bf(s1[j]); }
        a1[0] = t0.b; a1[1] = t1.b;
    } else {
#pragma unroll
        for (int kk = 0; kk < 2; ++kk) {
            int k = kk * 32 + g * 8;
            const float* p = sum + (long)tl * H + k;
            float4 f0 = *(const float4*)p;
            float4 f1 = *(const float4*)(p + 4);
            F8 t;
            t.u[0] = f2bf(f0.x); t.u[1] = f2bf(f0.y); t.u[2] = f2bf(f0.z); t.u[3] = f2bf(f0.w);
            t.u[4] = f2bf(f1.x); t.u[5] = f2bf(f1.y); t.u[6] = f2bf(f1.z); t.u[7] = f2bf(f1.w);
            a1[kk] = t.b;
        }
    }
#pragma unroll
    for (int kk = 2; kk < 4; ++kk) {
        if (NSB) {
            const u16* prow = nsb + (long)tl * H;
            F8 t; t.q = *(const uint4*)(prow + (kk - 2) * 32 + g * 8);
            a1[kk] = t.b;
        } else {
            int k = (kk - 2) * 32 + g * 8;
            const float* p = ns + (long)tl * H + k;
            float4 f0 = *(const float4*)p;
            float4 f1 = *(const float4*)(p + 4);
            F8 t;
            t.u[0] = f2bf(f0.x); t.u[1] = f2bf(f0.y); t.u[2] = f2bf(f0.z); t.u[3] = f2bf(f0.w);
            t.u[4] = f2bf(f1.x); t.u[5] = f2bf(f1.y); t.u[6] = f2bf(f1.z); t.u[7] = f2bf(f1.w);
            a1[kk] = t.b;
        }
    }

    float bias1[8], bias2[4];
#pragma unroll
    for (int j = 0; j < 8; ++j) bias1[j] = bu1[j * 16 + lr];
#pragma unroll
    for (int j = 0; j < 4; ++j) bias2[j] = bu2[j * 16 + lr];

    __syncthreads();

#pragma unroll
    for (int j = 0; j < 8; ++j) {
        f32x4 acc = {0.f, 0.f, 0.f, 0.f};
#pragma unroll
        for (int kk = 0; kk < 4; ++kk) {
            F8 bf; bf.q = *(const uint4*)((const char*)Wl + swz(j * 16 + lr, kk * 32 + g * 8, 128));
            acc = __builtin_amdgcn_mfma_f32_16x16x32_bf16(a1[kk], bf.b, acc, 0, 0, 0);
        }
#pragma unroll
        for (int r = 0; r < 4; ++r) {
            float vv = acc[r] + bias1[j];
            vv = vv > 0.f ? vv : 0.f;
            int row = w * 16 + g * 4 + r;
            *(u16*)((char*)h + swz(row, j * 16 + lr, 128)) = f2bf(vv);
        }
    }

    bf16x8 a2[4];
#pragma unroll
    for (int kk = 0; kk < 4; ++kk) {
        int row = w * 16 + lr;
        F8 t; t.q = *(const uint4*)((const char*)h + swz(row, kk * 32 + g * 8, 128));
        a2[kk] = t.b;
    }

    const char* W2base = (const char*)(Wl + 128 * 128);
#pragma unroll
    for (int j = 0; j < 4; ++j) {
        f32x4 acc = {0.f, 0.f, 0.f, 0.f};
#pragma unroll
        for (int kk = 0; kk < 4; ++kk) {
            F8 bf; bf.q = *(const uint4*)(W2base + swz(j * 16 + lr, kk * 32 + g * 8, 128));
            acc = __builtin_amdgcn_mfma_f32_16x16x32_bf16(a2[kk], bf.b, acc, 0, 0, 0);
        }
#pragma unroll
        for (int r = 0; r < 4; ++r) {
            int t = tile + w * 16 + g * 4 + r;
            if (t < N) out[(long)t * H + j * 16 + lr] = acc[r] + bias2[j];
        }
    }
}

// ---------------- launcher ----------------
extern "C" void kernel_launch(void* const* d_in, const int* in_sizes, int n_in,
                              void* d_out, int out_size, void* d_ws, size_t ws_size,
                              hipStream_t stream) {
    const float* ns = (const float*)d_in[0];
    const int* idxs[3] = { (const int*)d_in[1], (const int*)d_in[6], (const int*)d_in[11] };
    const float* b1s[3] = { (const float*)d_in[3], (const float*)d_in[8], (const float*)d_in[13] };
    const float* b2s[3] = { (const float*)d_in[5], (const float*)d_in[10], (const float*)d_in[15] };
    const float* bu1 = (const float*)d_in[17];
    const float* bu2 = (const float*)d_in[19];

    const int N = in_sizes[0] / H;
    const int Ts[3] = { in_sizes[1], in_sizes[6] / 2, in_sizes[11] / 3 };
    const int Ms[3] = { Ts[0] * 1, Ts[1] * 2, Ts[2] * 3 };
    const long Mtot = (long)Ms[0] + Ms[1] + Ms[2];

    char* wsb = (char*)d_ws;
    auto AL = [](size_t x) { return (x + 255) & ~(size_t)255; };

    const unsigned O_W1R0 = 0;
    const unsigned O_W2R0 = O_W1R0 + 64 * 64 * 2;
    const unsigned O_W1R1 = O_W2R0 + 64 * 64 * 2;
    const unsigned O_W2R1 = O_W1R1 + 128 * 128 * 2;
    const unsigned O_W1R2 = O_W2R1 + 128 * 128 * 2;
    const unsigned O_W2R2 = O_W1R2 + 192 * 192 * 2;
    const unsigned O_WU1  = O_W2R2 + 192 * 192 * 2;
    const unsigned O_WU2  = O_WU1 + 128 * 128 * 2;
    const size_t  wEnd    = O_WU2 + 128 * 64 * 2;
    const unsigned wOff1[3] = { O_W1R0, O_W1R1, O_W1R2 };
    const unsigned wOff2[3] = { O_W2R0, O_W2R1, O_W2R2 };

    const int nb = (N + 511) / 512;

    const size_t O_CNT = AL(wEnd);                       // becomes base after scan
    const size_t O_OFF = AL(O_CNT + (size_t)N * 4);      // rank cursor
    const size_t O_SUM = AL(O_OFF + (size_t)N * 4);
    const size_t O_POS = AL(O_SUM + (size_t)nb * 4);
    const size_t O_NSB = AL(O_POS + (size_t)Mtot * 4);
    const size_t nsLen = (size_t)N * H * 2;
    const size_t O_MSG = AL(O_NSB + nsLen);
    const size_t need  = O_MSG + (size_t)Mtot * 128;

    const bool sorted = (nb <= 512) && (ws_size >= need);
    const bool nsbOk  = ws_size >= O_NSB + nsLen;

    Segs segs;
    segs.s[0] = {(const float*)d_in[2],  O_W1R0, 64, 64};
    segs.s[1] = {(const float*)d_in[4],  O_W2R0, 64, 64};
    segs.s[2] = {(const float*)d_in[7],  O_W1R1, 128, 128};
    segs.s[3] = {(const float*)d_in[9],  O_W2R1, 128, 128};
    segs.s[4] = {(const float*)d_in[12], O_W1R2, 192, 192};
    segs.s[5] = {(const float*)d_in[14], O_W2R2, 192, 192};
    segs.s[6] = {(const float*)d_in[16], O_WU1, 128, 128};
    segs.s[7] = {(const float*)d_in[18], O_WU2, 128, 64};

    conv_weights<<<dim3(36, 8), 256, 0, stream>>>(segs, wsb);

    float* dout = (float*)d_out;
    u16* nsbp = (u16*)(wsb + O_NSB);

    const u16* W1[3] = { (const u16*)(wsb + wOff1[0]), (const u16*)(wsb + wOff1[1]), (const u16*)(wsb + wOff1[2]) };
    const u16* W2[3] = { (const u16*)(wsb + wOff2[0]), (const u16*)(wsb + wOff2[1]), (const u16*)(wsb + wOff2[2]) };

    auto gT  = [](int T) { return (T + 127) / 128; };
    auto gTm = [](int T) { return (T + 255) / 256; };

    if (sorted) {
        u32* cnt = (u32*)(wsb + O_CNT);   // exclusive base after scan
        u32* off = (u32*)(wsb + O_OFF);
        u32* sums = (u32*)(wsb + O_SUM);
        u32* pos = (u32*)(wsb + O_POS);
        u16* msg = (u16*)(wsb + O_MSG);

        I3 h3; for (int r = 0; r < 3; ++r) { h3.idx[r] = idxs[r]; h3.m[r] = Ms[r]; }

        hipMemsetAsync(cnt, 0, (size_t)N * 4, stream);
        CNH cnh; cnh.src = (const float4*)ns; cnh.dst = (ushort4*)nsbp;
        cnh.n4 = N * H / 4; cnh.h = h3; cnh.cnt = cnt;
        conv_nodes_hist<<<dim3(512, 4), 256, 0, stream>>>(cnh);

        scan_blocks<<<nb, 512, 0, stream>>>(cnt, sums, N);
        scan_sums<<<1, 512, 0, stream>>>(sums, nb);
        scan_add2<<<nb, 512, 0, stream>>>(cnt, off, sums, N);
        rank_all<<<dim3(512, 3), 256, 0, stream>>>(h3, off, pos);

        msg_kernel<1><<<gTm(Ts[0]), 512, 0, stream>>>(
            nsbp, idxs[0], pos, W1[0], b1s[0], W2[0], b2s[0], msg, Ts[0]);
        msg_kernel<2><<<gTm(Ts[1]), 512, 0, stream>>>(
            nsbp, idxs[1], pos + Ms[0], W1[1], b1s[1], W2[1], b2s[1], msg, Ts[1]);
        msg_kernel<3><<<gTm(Ts[2]), 512, 0, stream>>>(
            nsbp, idxs[2], pos + Ms[0] + Ms[1], W1[2], b1s[2], W2[2], b2s[2], msg, Ts[2]);

        update_kernel<true, true><<<(N + 127) / 128, 512, 0, stream>>>(
            ns, nsbp, nullptr, cnt, msg, (int)Mtot,
            (const u16*)(wsb + O_WU1), bu1, (const u16*)(wsb + O_WU2), bu2, dout, N);
    } else {
        if (nsbOk) {
            CNH cnh; cnh.src = (const float4*)ns; cnh.dst = (ushort4*)nsbp;
            cnh.n4 = N * H / 4;
            for (int r = 0; r < 3; ++r) { cnh.h.idx[r] = idxs[0]; cnh.h.m[r] = 0; }
            cnh.cnt = (u32*)(wsb + O_CNT);
            conv_nodes_hist<<<dim3(512, 1), 256, 0, stream>>>(cnh);
        }
        hipMemsetAsync(dout, 0, (size_t)N * H * sizeof(float), stream);
        for (int r = 0; r < 3; ++r) {
            const int T = Ts[r], nbl = gT(T);
            if (nsbOk) {
                if (r == 0) rel_kernel<1, true><<<nbl, 512, 0, stream>>>(ns, nsbp, idxs[0], W1[0], b1s[0], W2[0], b2s[0], dout, T);
                if (r == 1) rel_kernel<2, true><<<nbl, 512, 0, stream>>>(ns, nsbp, idxs[1], W1[1], b1s[1], W2[1], b2s[1], dout, T);
                if (r == 2) rel_kernel<3, true><<<nbl, 512, 0, stream>>>(ns, nsbp, idxs[2], W1[2], b1s[2], W2[2], b2s[2], dout, T);
            } else {
                if (r == 0) rel_kernel<1, false><<<nbl, 512, 0, stream>>>(ns, nullptr, idxs[0], W1[0], b1s[0], W2[0], b2s[0], dout, T);
                if (r == 1) rel_kernel<2, false><<<nbl, 512, 0, stream>>>(ns, nullptr, idxs[1], W1[1], b1s[1], W2[1], b2s[1], dout, T);
                if (r == 2) rel_kernel<3, false><<<nbl, 512, 0, stream>>>(ns, nullptr, idxs[2], W1[2], b1s[2], W2[2], b2s[2], dout, T);
            }
        }
        if (nsbOk)
            update_kernel<false, true><<<(N + 127) / 128, 512, 0, stream>>>(
                ns, nsbp, dout, nullptr, nullptr, 0,
                (const u16*)(wsb + O_WU1), bu1, (const u16*)(wsb + O_WU2), bu2, dout, N);
        else
            update_kernel<false, false><<<(N + 127) / 128, 512, 0, stream>>>(
                ns, nullptr, dout, nullptr, nullptr, 0,
                (const u16*)(wsb + O_WU1), bu1, (const u16*)(wsb + O_WU2), bu2, dout, N);
    }
}

// Round 3
// 332.669 us; speedup vs baseline: 1.3157x; 1.1022x over previous
//
#include <hip/hip_runtime.h>

#define H 64

typedef __attribute__((ext_vector_type(8))) __bf16 bf16x8;
typedef __attribute__((ext_vector_type(4))) float f32x4;
typedef unsigned short u16;
typedef unsigned int u32;

union F8 { bf16x8 b; u16 u[8]; uint4 q; };

__device__ __forceinline__ u16 f2bf(float f) {
    union { float f; u32 u; } v; v.f = f;
    u32 r = v.u + 0x7FFF + ((v.u >> 16) & 1);   // RNE
    return (u16)(r >> 16);
}
__device__ __forceinline__ float bf2f(u16 x) {
    return __uint_as_float((u32)x << 16);
}
// Swizzled layout: element (col,k) at byte ((col*K+k)*2) ^ ((col&7)<<4).
__device__ __forceinline__ unsigned swz(int col, int k, int K) {
    return ((unsigned)(col * K + k) * 2u) ^ (((unsigned)col & 7u) << 4);
}

// ---------------- weight convert ----------------
struct Seg { const float* src; unsigned dstBytes; int K; int N; };
struct Segs { Seg s[8]; };

__global__ __launch_bounds__(256) void conv_weights(Segs segs, char* out) {
    Seg sg = segs.s[blockIdx.y];
    int total = sg.K * sg.N;
    char* dst = out + sg.dstBytes;
    for (int e = blockIdx.x * 256 + threadIdx.x; e < total; e += gridDim.x * 256) {
        int k = e / sg.N, n = e % sg.N;
        *(u16*)(dst + swz(n, k, sg.K)) = f2bf(sg.src[e]);
    }
}

// ---------------- fused: node f32->bf16 convert + destination histogram ----------------
struct I3 { const int* idx[3]; int m[3]; };
struct CNH { const float4* src; ushort4* dst; int n4; I3 h; u32* cnt; };

__global__ __launch_bounds__(256) void conv_nodes_hist(CNH a) {
    if (blockIdx.y == 0) {
        for (int i = blockIdx.x * 256 + threadIdx.x; i < a.n4; i += gridDim.x * 256) {
            float4 f = a.src[i];
            ushort4 o;
            o.x = f2bf(f.x); o.y = f2bf(f.y); o.z = f2bf(f.z); o.w = f2bf(f.w);
            a.dst[i] = o;
        }
    } else {
        const int r = blockIdx.y - 1;
        const int* idx = a.h.idx[r];
        const int M = a.h.m[r];
        for (int i = blockIdx.x * 256 + threadIdx.x; i < M; i += gridDim.x * 256)
            atomicAdd(a.cnt + idx[i], 1u);
    }
}

// ---------------- scan (3 kernels); scan_add2 emits base AND the rank cursor ----------------
__global__ __launch_bounds__(512) void scan_blocks(u32* __restrict__ data,
                                                   u32* __restrict__ sums, int n) {
    __shared__ u32 s[512];
    int tid = threadIdx.x, i = blockIdx.x * 512 + tid;
    u32 v = (i < n) ? data[i] : 0u;
    s[tid] = v; __syncthreads();
    for (int d = 1; d < 512; d <<= 1) {
        u32 t = (tid >= d) ? s[tid - d] : 0u; __syncthreads();
        s[tid] += t; __syncthreads();
    }
    if (i < n) data[i] = s[tid] - v;               // exclusive
    if (tid == 511) sums[blockIdx.x] = s[511];
}

__global__ __launch_bounds__(512) void scan_sums(u32* __restrict__ sums, int nb) {
    __shared__ u32 s[512];
    int tid = threadIdx.x;
    u32 v = (tid < nb) ? sums[tid] : 0u;
    s[tid] = v; __syncthreads();
    for (int d = 1; d < 512; d <<= 1) {
        u32 t = (tid >= d) ? s[tid - d] : 0u; __syncthreads();
        s[tid] += t; __syncthreads();
    }
    if (tid < nb) sums[tid] = s[tid] - v;          // exclusive
}

__global__ __launch_bounds__(512) void scan_add2(u32* __restrict__ data,
                                                 u32* __restrict__ off,
                                                 const u32* __restrict__ sums, int n) {
    int i = blockIdx.x * 512 + threadIdx.x;
    if (i < n) { u32 v = data[i] + sums[blockIdx.x]; data[i] = v; off[i] = v; }
}

// pos[segOff + i] = sorted slot of message i of relation blockIdx.y
__global__ __launch_bounds__(256) void rank_all(I3 h, u32* __restrict__ off,
                                                u32* __restrict__ pos) {
    const int r = blockIdx.y;
    const int* idx = h.idx[r];
    const int M = h.m[r];
    u32* p = pos;
    for (int q = 0; q < r; ++q) p += h.m[q];
    for (int i = blockIdx.x * 256 + threadIdx.x; i < M; i += gridDim.x * 256)
        p[i] = atomicAdd(off + idx[i], 1u);
}

// ================= msg kernel: fused MLP -> msg[pos[m]] =================
// R16: R13 16-row-wave structure (proven best for msg<1>/msg<2>), with W
// staged in COLUMN-THIRDS for A=3: Wl 73.7KB -> 24.5KB, total LDS 72KB ->
// 2 blocks/CU (16 waves, VGPR=88 permits exactly that). R15 showed B-read
// halving buys only ~7% -> the limiter is latency at 8 waves/CU; occupancy
// is the lever. A=1: DUAL (W1+W2 upfront, 1 barrier). A=2: full-stage
// (VGPR caps occupancy at 2 blocks anyway; chunking = barriers for nothing).
// __launch_bounds__(512,4): pin VGPR<=128, never spill (R14 lesson).
template<int A>
__global__ __launch_bounds__(512, 4) void msg_kernel(
    const u16* __restrict__ nsb, const int* __restrict__ idx,
    const u32* __restrict__ pos,
    const u16* __restrict__ w1T, const float* __restrict__ b1,
    const u16* __restrict__ w2T, const float* __restrict__ b2,
    u16* __restrict__ msg, int T)
{
    constexpr int D   = A * 64;
    constexpr int KS  = D / 32;            // k-steps of 32
    constexpr int NT  = D / 16;            // 16-col tiles total
    constexpr bool DUAL = (A == 1);        // W1+W2 staged upfront
    constexpr int WH  = (A == 3) ? 3 : 1;  // W column-chunks per GEMM
    constexpr int NTH = NT / WH;           // col tiles per chunk
    constexpr int COLH = D / WH;           // cols per chunk
    __shared__ __align__(16) u16 Wl[DUAL ? 2 * D * D : COLH * D];
    __shared__ __align__(16) u16 h1[128 * D];      // H1, later reused as msg staging

    const int tid  = threadIdx.x;
    const int lane = tid & 63;
    const int w    = tid >> 6;
    const int g    = lane >> 4;
    const int lr   = lane & 15;

    const int tile = blockIdx.x * 128;
    const int trow = tile + w * 16 + lr;
    const int tl   = trow < T ? trow : T - 1;

    // gather A fragments (wave owns atoms [w*16, w*16+16))
    int nodes[A];
#pragma unroll
    for (int s = 0; s < A; ++s) nodes[s] = idx[(long)tl * A + s];

    bf16x8 a1[KS];
#pragma unroll
    for (int kk = 0; kk < KS; ++kk) {
        const u16* p = nsb + (long)nodes[kk >> 1] * H + ((kk & 1) * 32 + g * 8);
        F8 t; t.q = *(const uint4*)p;
        a1[kk] = t.b;
    }

    float bias1[NT], bias2[NT];
#pragma unroll
    for (int j = 0; j < NT; ++j) bias1[j] = b1[j * 16 + lr];
#pragma unroll
    for (int j = 0; j < NT; ++j) bias2[j] = b2[j * 16 + lr];

    // ---- GEMM1 over W1 column-chunks ----
#pragma unroll
    for (int hh = 0; hh < WH; ++hh) {
        if constexpr (DUAL) {
            // stage W1+W2 together (adjacent in workspace)
            const uint4* s4 = (const uint4*)w1T;
            uint4* d4 = (uint4*)Wl;
#pragma unroll
            for (int i = 0; i < 2 * D * D / 8 / 512; ++i) d4[i * 512 + tid] = s4[i * 512 + tid];
        } else {
            const uint4* s4 = (const uint4*)(w1T + (size_t)hh * COLH * D);
            uint4* d4 = (uint4*)Wl;
#pragma unroll
            for (int i = 0; i < COLH * D / 8 / 512; ++i) d4[i * 512 + tid] = s4[i * 512 + tid];
        }
        __syncthreads();                           // chunk resident

#pragma unroll
        for (int j = 0; j < NTH; ++j) {
            const int jg = hh * NTH + j;
            f32x4 acc = {0.f, 0.f, 0.f, 0.f};
#pragma unroll
            for (int kk = 0; kk < KS; ++kk) {
                F8 bf; bf.q = *(const uint4*)((const char*)Wl + swz(j * 16 + lr, kk * 32 + g * 8, D));
                acc = __builtin_amdgcn_mfma_f32_16x16x32_bf16(a1[kk], bf.b, acc, 0, 0, 0);
            }
#pragma unroll
            for (int r = 0; r < 4; ++r) {
                float vv = acc[r] + bias1[jg];
                vv = vv > 0.f ? vv : 0.f;
                int row = w * 16 + g * 4 + r;
                *(u16*)((char*)h1 + swz(row, jg * 16 + lr, D)) = f2bf(vv);
            }
        }
        if constexpr (!DUAL) __syncthreads();      // chunk reads done before overwrite
    }

    // a2 fragments: own-wave h1 rows (same-wave writes; lgkmcnt ordering suffices)
    bf16x8 a2[KS];
#pragma unroll
    for (int kk = 0; kk < KS; ++kk) {
        int row = w * 16 + lr;
        F8 t; t.q = *(const uint4*)((const char*)h1 + swz(row, kk * 32 + g * 8, D));
        a2[kk] = t.b;
    }

    // ---- GEMM2 over W2 column-chunks -> stage msg rows into own h1 region ----
#pragma unroll
    for (int hh = 0; hh < WH; ++hh) {
        if constexpr (!DUAL) {
            const uint4* s4 = (const uint4*)(w2T + (size_t)hh * COLH * D);
            uint4* d4 = (uint4*)Wl;
#pragma unroll
            for (int i = 0; i < COLH * D / 8 / 512; ++i) d4[i * 512 + tid] = s4[i * 512 + tid];
            __syncthreads();                       // chunk resident
        }
        const char* W2base = DUAL ? (const char*)(Wl + D * D) : (const char*)Wl;

#pragma unroll
        for (int j = 0; j < NTH; ++j) {
            const int jg = hh * NTH + j;
            f32x4 acc = {0.f, 0.f, 0.f, 0.f};
#pragma unroll
            for (int kk = 0; kk < KS; ++kk) {
                F8 bf; bf.q = *(const uint4*)(W2base + swz(j * 16 + lr, kk * 32 + g * 8, D));
                acc = __builtin_amdgcn_mfma_f32_16x16x32_bf16(a2[kk], bf.b, acc, 0, 0, 0);
            }
            const int gc   = jg * 16 + lr;         // global output col in D
            const int slot = gc >> 6;              // 64-col message slot
            const int cs   = gc & 63;
#pragma unroll
            for (int r = 0; r < 4; ++r) {
                int la   = w * 16 + g * 4 + r;     // local atom
                int mrow = la * A + slot;          // local message row
                unsigned byte = (((unsigned)(mrow * 64 + cs)) * 2u) ^ (((unsigned)mrow & 7u) << 4);
                *(u16*)((char*)h1 + byte) = f2bf(acc[r] + bias2[jg]);
            }
        }
        if constexpr (!DUAL) { if (hh + 1 < WH) __syncthreads(); }   // before overwrite
    }

    // stream own-wave message rows to sorted positions (pos lookup only)
    const int  mbase = (tile + w * 16) * A;        // relation-local message id base
    const bool full  = (tile + 128 <= T);
#pragma unroll
    for (int i = 0; i < 16 * A; i += 4) {
        int ml   = i + (lane >> 4);                // local message row in wave
        int mrow = w * 16 * A + ml;
        bool ok  = full || ((tile + w * 16 + ml / A) < T);
        if (ok) {
            u32 p = pos[mbase + ml];
            unsigned byte = (((unsigned)(mrow * 64 + (lane & 15) * 4)) * 2u) ^ (((unsigned)mrow & 7u) << 4);
            uint2 v = *(const uint2*)((const char*)h1 + byte);
            *(uint2*)(msg + (size_t)p * 64 + (lane & 15) * 4) = v;
        }
    }
}

// ================= fallback: fused with f32 atomics into d_out =================
template<int A, bool NSB>
__global__ __launch_bounds__(512) void rel_kernel(
    const float* __restrict__ ns, const u16* __restrict__ nsb,
    const int* __restrict__ idx,
    const u16* __restrict__ w1T, const float* __restrict__ b1,
    const u16* __restrict__ w2T, const float* __restrict__ b2,
    float* __restrict__ dout, int T)
{
    constexpr int D  = A * 64;
    constexpr int KS = D / 32;
    constexpr int NT = D / 16;
    constexpr bool DUAL = (A == 1);
    __shared__ __align__(16) u16 Wl[(DUAL ? 2 : 1) * D * D];
    __shared__ __align__(16) u16 h1[128 * D];

    const int tid  = threadIdx.x;
    const int lane = tid & 63;
    const int w    = tid >> 6;
    const int g    = lane >> 4;
    const int lr   = lane & 15;

    const int tile = blockIdx.x * 128;
    const int trow = tile + w * 16 + lr;
    const int tl   = trow < T ? trow : T - 1;

    {
        constexpr int NV = (DUAL ? 2 : 1) * D * D / 8;
        const uint4* s4 = (const uint4*)w1T;
        uint4* d4 = (uint4*)Wl;
#pragma unroll
        for (int i = 0; i < NV / 512; ++i) d4[i * 512 + tid] = s4[i * 512 + tid];
    }

    int nodes[A];
#pragma unroll
    for (int s = 0; s < A; ++s) nodes[s] = idx[(long)tl * A + s];

    bf16x8 a1[KS];
#pragma unroll
    for (int kk = 0; kk < KS; ++kk) {
        if constexpr (NSB) {
            const u16* p = nsb + (long)nodes[kk >> 1] * H + ((kk & 1) * 32 + g * 8);
            F8 t; t.q = *(const uint4*)p;
            a1[kk] = t.b;
        } else {
            const float* p = ns + (long)nodes[kk >> 1] * H + ((kk & 1) * 32 + g * 8);
            float4 f0 = *(const float4*)p;
            float4 f1 = *(const float4*)(p + 4);
            F8 t;
            t.u[0] = f2bf(f0.x); t.u[1] = f2bf(f0.y); t.u[2] = f2bf(f0.z); t.u[3] = f2bf(f0.w);
            t.u[4] = f2bf(f1.x); t.u[5] = f2bf(f1.y); t.u[6] = f2bf(f1.z); t.u[7] = f2bf(f1.w);
            a1[kk] = t.b;
        }
    }

    float bias1[NT];
#pragma unroll
    for (int j = 0; j < NT; ++j) bias1[j] = b1[j * 16 + lr];

    __syncthreads();

#pragma unroll
    for (int j = 0; j < NT; ++j) {
        f32x4 acc = {0.f, 0.f, 0.f, 0.f};
#pragma unroll
        for (int kk = 0; kk < KS; ++kk) {
            F8 bf; bf.q = *(const uint4*)((const char*)Wl + swz(j * 16 + lr, kk * 32 + g * 8, D));
            acc = __builtin_amdgcn_mfma_f32_16x16x32_bf16(a1[kk], bf.b, acc, 0, 0, 0);
        }
#pragma unroll
        for (int r = 0; r < 4; ++r) {
            float vv = acc[r] + bias1[j];
            vv = vv > 0.f ? vv : 0.f;
            int row = w * 16 + g * 4 + r;
            *(u16*)((char*)h1 + swz(row, j * 16 + lr, D)) = f2bf(vv);
        }
    }

    const char* W2base;
    if constexpr (!DUAL) {
        __syncthreads();
        const uint4* s4 = (const uint4*)w2T;
        uint4* d4 = (uint4*)Wl;
        constexpr int NV = D * D / 8;
#pragma unroll
        for (int i = 0; i < NV / 512; ++i) d4[i * 512 + tid] = s4[i * 512 + tid];
        W2base = (const char*)Wl;
    } else {
        W2base = (const char*)(Wl + D * D);
    }

    bf16x8 a2[KS];
#pragma unroll
    for (int kk = 0; kk < KS; ++kk) {
        int row = w * 16 + lr;
        F8 t; t.q = *(const uint4*)((const char*)h1 + swz(row, kk * 32 + g * 8, D));
        a2[kk] = t.b;
    }

    float bias2[NT];
#pragma unroll
    for (int j = 0; j < NT; ++j) bias2[j] = b2[j * 16 + lr];

    int  nodes2[A][4];
    bool pred[4];
#pragma unroll
    for (int r = 0; r < 4; ++r) {
        int t  = tile + w * 16 + g * 4 + r;
        int tc = t < T ? t : T - 1;
        pred[r] = t < T;
#pragma unroll
        for (int s = 0; s < A; ++s) nodes2[s][r] = idx[(long)tc * A + s];
    }
    if constexpr (!DUAL) __syncthreads();

#pragma unroll
    for (int j = 0; j < NT; ++j) {
        f32x4 acc = {0.f, 0.f, 0.f, 0.f};
#pragma unroll
        for (int kk = 0; kk < KS; ++kk) {
            F8 bf; bf.q = *(const uint4*)(W2base + swz(j * 16 + lr, kk * 32 + g * 8, D));
            acc = __builtin_amdgcn_mfma_f32_16x16x32_bf16(a2[kk], bf.b, acc, 0, 0, 0);
        }
        const int slot = j >> 2;
        const int coff = (j & 3) * 16 + lr;
#pragma unroll
        for (int r = 0; r < 4; ++r) {
            if (pred[r])
                unsafeAtomicAdd(dout + (long)nodes2[slot][r] * H + coff, acc[r] + bias2[j]);
        }
    }
}

// ---------------- update: fused segment-sum (SEG) + 2-layer MLP ----------------
template<bool SEG, bool NSB>
__global__ __launch_bounds__(512) void update_kernel(
    const float* __restrict__ ns, const u16* __restrict__ nsb,
    const float* __restrict__ sum,
    const u32* __restrict__ base, const u16* __restrict__ msg, int Mtot,
    const u16* __restrict__ wu1T, const float* __restrict__ bu1,
    const u16* __restrict__ wu2T, const float* __restrict__ bu2,
    float* __restrict__ out, int N)
{
    __shared__ __align__(16) u16 Wl[128 * 128 + 64 * 128];
    __shared__ __align__(16) u16 h[128 * 128];

    const int tid  = threadIdx.x;
    const int lane = tid & 63;
    const int w    = tid >> 6;
    const int g    = lane >> 4;
    const int lr   = lane & 15;

    {
        const uint4* s4 = (const uint4*)wu1T;
        uint4* d4 = (uint4*)Wl;
#pragma unroll
        for (int i = 0; i < 6; ++i) d4[i * 512 + tid] = s4[i * 512 + tid];
    }

    const int tile = blockIdx.x * 128;
    const int trow = tile + w * 16 + lr;
    const int tl   = trow < N ? trow : N - 1;

    bf16x8 a1[4];
    if constexpr (SEG) {
        const u32 s = base[tl];
        const u32 e = (tl + 1 < N) ? base[tl + 1] : (u32)Mtot;
        float s0[8], s1[8];
#pragma unroll
        for (int j = 0; j < 8; ++j) { s0[j] = 0.f; s1[j] = 0.f; }
        for (u32 p = s; p < e; ++p) {
            const u16* row = msg + (size_t)p * 64;
            F8 v0, v1;
            v0.q = *(const uint4*)(row + g * 8);
            v1.q = *(const uint4*)(row + 32 + g * 8);
#pragma unroll
            for (int j = 0; j < 8; ++j) { s0[j] += bf2f(v0.u[j]); s1[j] += bf2f(v1.u[j]); }
        }
        F8 t0, t1;
#pragma unroll
        for (int j = 0; j < 8; ++j) { t0.u[j] = f2bf(s0[j]); t1.u[j] = f2bf(s1[j]); }
        a1[0] = t0.b; a1[1] = t1.b;
    } else {
#pragma unroll
        for (int kk = 0; kk < 2; ++kk) {
            int k = kk * 32 + g * 8;
            const float* p = sum + (long)tl * H + k;
            float4 f0 = *(const float4*)p;
            float4 f1 = *(const float4*)(p + 4);
            F8 t;
            t.u[0] = f2bf(f0.x); t.u[1] = f2bf(f0.y); t.u[2] = f2bf(f0.z); t.u[3] = f2bf(f0.w);
            t.u[4] = f2bf(f1.x); t.u[5] = f2bf(f1.y); t.u[6] = f2bf(f1.z); t.u[7] = f2bf(f1.w);
            a1[kk] = t.b;
        }
    }
#pragma unroll
    for (int kk = 2; kk < 4; ++kk) {
        if (NSB) {
            const u16* prow = nsb + (long)tl * H;
            F8 t; t.q = *(const uint4*)(prow + (kk - 2) * 32 + g * 8);
            a1[kk] = t.b;
        } else {
            int k = (kk - 2) * 32 + g * 8;
            const float* p = ns + (long)tl * H + k;
            float4 f0 = *(const float4*)p;
            float4 f1 = *(const float4*)(p + 4);
            F8 t;
            t.u[0] = f2bf(f0.x); t.u[1] = f2bf(f0.y); t.u[2] = f2bf(f0.z); t.u[3] = f2bf(f0.w);
            t.u[4] = f2bf(f1.x); t.u[5] = f2bf(f1.y); t.u[6] = f2bf(f1.z); t.u[7] = f2bf(f1.w);
            a1[kk] = t.b;
        }
    }

    float bias1[8], bias2[4];
#pragma unroll
    for (int j = 0; j < 8; ++j) bias1[j] = bu1[j * 16 + lr];
#pragma unroll
    for (int j = 0; j < 4; ++j) bias2[j] = bu2[j * 16 + lr];

    __syncthreads();

#pragma unroll
    for (int j = 0; j < 8; ++j) {
        f32x4 acc = {0.f, 0.f, 0.f, 0.f};
#pragma unroll
        for (int kk = 0; kk < 4; ++kk) {
            F8 bf; bf.q = *(const uint4*)((const char*)Wl + swz(j * 16 + lr, kk * 32 + g * 8, 128));
            acc = __builtin_amdgcn_mfma_f32_16x16x32_bf16(a1[kk], bf.b, acc, 0, 0, 0);
        }
#pragma unroll
        for (int r = 0; r < 4; ++r) {
            float vv = acc[r] + bias1[j];
            vv = vv > 0.f ? vv : 0.f;
            int row = w * 16 + g * 4 + r;
            *(u16*)((char*)h + swz(row, j * 16 + lr, 128)) = f2bf(vv);
        }
    }

    bf16x8 a2[4];
#pragma unroll
    for (int kk = 0; kk < 4; ++kk) {
        int row = w * 16 + lr;
        F8 t; t.q = *(const uint4*)((const char*)h + swz(row, kk * 32 + g * 8, 128));
        a2[kk] = t.b;
    }

    const char* W2base = (const char*)(Wl + 128 * 128);
#pragma unroll
    for (int j = 0; j < 4; ++j) {
        f32x4 acc = {0.f, 0.f, 0.f, 0.f};
#pragma unroll
        for (int kk = 0; kk < 4; ++kk) {
            F8 bf; bf.q = *(const uint4*)(W2base + swz(j * 16 + lr, kk * 32 + g * 8, 128));
            acc = __builtin_amdgcn_mfma_f32_16x16x32_bf16(a2[kk], bf.b, acc, 0, 0, 0);
        }
#pragma unroll
        for (int r = 0; r < 4; ++r) {
            int t = tile + w * 16 + g * 4 + r;
            if (t < N) out[(long)t * H + j * 16 + lr] = acc[r] + bias2[j];
        }
    }
}

// ---------------- launcher ----------------
extern "C" void kernel_launch(void* const* d_in, const int* in_sizes, int n_in,
                              void* d_out, int out_size, void* d_ws, size_t ws_size,
                              hipStream_t stream) {
    const float* ns = (const float*)d_in[0];
    const int* idxs[3] = { (const int*)d_in[1], (const int*)d_in[6], (const int*)d_in[11] };
    const float* b1s[3] = { (const float*)d_in[3], (const float*)d_in[8], (const float*)d_in[13] };
    const float* b2s[3] = { (const float*)d_in[5], (const float*)d_in[10], (const float*)d_in[15] };
    const float* bu1 = (const float*)d_in[17];
    const float* bu2 = (const float*)d_in[19];

    const int N = in_sizes[0] / H;
    const int Ts[3] = { in_sizes[1], in_sizes[6] / 2, in_sizes[11] / 3 };
    const int Ms[3] = { Ts[0] * 1, Ts[1] * 2, Ts[2] * 3 };
    const long Mtot = (long)Ms[0] + Ms[1] + Ms[2];

    char* wsb = (char*)d_ws;
    auto AL = [](size_t x) { return (x + 255) & ~(size_t)255; };

    const unsigned O_W1R0 = 0;
    const unsigned O_W2R0 = O_W1R0 + 64 * 64 * 2;
    const unsigned O_W1R1 = O_W2R0 + 64 * 64 * 2;
    const unsigned O_W2R1 = O_W1R1 + 128 * 128 * 2;
    const unsigned O_W1R2 = O_W2R1 + 128 * 128 * 2;
    const unsigned O_W2R2 = O_W1R2 + 192 * 192 * 2;
    const unsigned O_WU1  = O_W2R2 + 192 * 192 * 2;
    const unsigned O_WU2  = O_WU1 + 128 * 128 * 2;
    const size_t  wEnd    = O_WU2 + 128 * 64 * 2;
    const unsigned wOff1[3] = { O_W1R0, O_W1R1, O_W1R2 };
    const unsigned wOff2[3] = { O_W2R0, O_W2R1, O_W2R2 };

    const int nb = (N + 511) / 512;

    const size_t O_CNT = AL(wEnd);                       // becomes base after scan
    const size_t O_OFF = AL(O_CNT + (size_t)N * 4);      // rank cursor
    const size_t O_SUM = AL(O_OFF + (size_t)N * 4);
    const size_t O_POS = AL(O_SUM + (size_t)nb * 4);
    const size_t O_NSB = AL(O_POS + (size_t)Mtot * 4);
    const size_t nsLen = (size_t)N * H * 2;
    const size_t O_MSG = AL(O_NSB + nsLen);
    const size_t need  = O_MSG + (size_t)Mtot * 128;

    const bool sorted = (nb <= 512) && (ws_size >= need);
    const bool nsbOk  = ws_size >= O_NSB + nsLen;

    Segs segs;
    segs.s[0] = {(const float*)d_in[2],  O_W1R0, 64, 64};
    segs.s[1] = {(const float*)d_in[4],  O_W2R0, 64, 64};
    segs.s[2] = {(const float*)d_in[7],  O_W1R1, 128, 128};
    segs.s[3] = {(const float*)d_in[9],  O_W2R1, 128, 128};
    segs.s[4] = {(const float*)d_in[12], O_W1R2, 192, 192};
    segs.s[5] = {(const float*)d_in[14], O_W2R2, 192, 192};
    segs.s[6] = {(const float*)d_in[16], O_WU1, 128, 128};
    segs.s[7] = {(const float*)d_in[18], O_WU2, 128, 64};

    conv_weights<<<dim3(36, 8), 256, 0, stream>>>(segs, wsb);

    float* dout = (float*)d_out;
    u16* nsbp = (u16*)(wsb + O_NSB);

    const u16* W1[3] = { (const u16*)(wsb + wOff1[0]), (const u16*)(wsb + wOff1[1]), (const u16*)(wsb + wOff1[2]) };
    const u16* W2[3] = { (const u16*)(wsb + wOff2[0]), (const u16*)(wsb + wOff2[1]), (const u16*)(wsb + wOff2[2]) };

    auto gT = [](int T) { return (T + 127) / 128; };

    if (sorted) {
        u32* cnt = (u32*)(wsb + O_CNT);   // exclusive base after scan
        u32* off = (u32*)(wsb + O_OFF);
        u32* sums = (u32*)(wsb + O_SUM);
        u32* pos = (u32*)(wsb + O_POS);
        u16* msg = (u16*)(wsb + O_MSG);

        I3 h3; for (int r = 0; r < 3; ++r) { h3.idx[r] = idxs[r]; h3.m[r] = Ms[r]; }

        hipMemsetAsync(cnt, 0, (size_t)N * 4, stream);
        CNH cnh; cnh.src = (const float4*)ns; cnh.dst = (ushort4*)nsbp;
        cnh.n4 = N * H / 4; cnh.h = h3; cnh.cnt = cnt;
        conv_nodes_hist<<<dim3(512, 4), 256, 0, stream>>>(cnh);

        scan_blocks<<<nb, 512, 0, stream>>>(cnt, sums, N);
        scan_sums<<<1, 512, 0, stream>>>(sums, nb);
        scan_add2<<<nb, 512, 0, stream>>>(cnt, off, sums, N);
        rank_all<<<dim3(512, 3), 256, 0, stream>>>(h3, off, pos);

        msg_kernel<1><<<gT(Ts[0]), 512, 0, stream>>>(
            nsbp, idxs[0], pos, W1[0], b1s[0], W2[0], b2s[0], msg, Ts[0]);
        msg_kernel<2><<<gT(Ts[1]), 512, 0, stream>>>(
            nsbp, idxs[1], pos + Ms[0], W1[1], b1s[1], W2[1], b2s[1], msg, Ts[1]);
        msg_kernel<3><<<gT(Ts[2]), 512, 0, stream>>>(
            nsbp, idxs[2], pos + Ms[0] + Ms[1], W1[2], b1s[2], W2[2], b2s[2], msg, Ts[2]);

        update_kernel<true, true><<<(N + 127) / 128, 512, 0, stream>>>(
            ns, nsbp, nullptr, cnt, msg, (int)Mtot,
            (const u16*)(wsb + O_WU1), bu1, (const u16*)(wsb + O_WU2), bu2, dout, N);
    } else {
        if (nsbOk) {
            CNH cnh; cnh.src = (const float4*)ns; cnh.dst = (ushort4*)nsbp;
            cnh.n4 = N * H / 4;
            for (int r = 0; r < 3; ++r) { cnh.h.idx[r] = idxs[0]; cnh.h.m[r] = 0; }
            cnh.cnt = (u32*)(wsb + O_CNT);
            conv_nodes_hist<<<dim3(512, 1), 256, 0, stream>>>(cnh);
        }
        hipMemsetAsync(dout, 0, (size_t)N * H * sizeof(float), stream);
        for (int r = 0; r < 3; ++r) {
            const int T = Ts[r], nbl = gT(T);
            if (nsbOk) {
                if (r == 0) rel_kernel<1, true><<<nbl, 512, 0, stream>>>(ns, nsbp, idxs[0], W1[0], b1s[0], W2[0], b2s[0], dout, T);
                if (r == 1) rel_kernel<2, true><<<nbl, 512, 0, stream>>>(ns, nsbp, idxs[1], W1[1], b1s[1], W2[1], b2s[1], dout, T);
                if (r == 2) rel_kernel<3, true><<<nbl, 512, 0, stream>>>(ns, nsbp, idxs[2], W1[2], b1s[2], W2[2], b2s[2], dout, T);
            } else {
                if (r == 0) rel_kernel<1, false><<<nbl, 512, 0, stream>>>(ns, nullptr, idxs[0], W1[0], b1s[0], W2[0], b2s[0], dout, T);
                if (r == 1) rel_kernel<2, false><<<nbl, 512, 0, stream>>>(ns, nullptr, idxs[1], W1[1], b1s[1], W2[1], b2s[1], dout, T);
                if (r == 2) rel_kernel<3, false><<<nbl, 512, 0, stream>>>(ns, nullptr, idxs[2], W1[2], b1s[2], W2[2], b2s[2], dout, T);
            }
        }
        if (nsbOk)
            update_kernel<false, true><<<(N + 127) / 128, 512, 0, stream>>>(
                ns, nsbp, dout, nullptr, nullptr, 0,
                (const u16*)(wsb + O_WU1), bu1, (const u16*)(wsb + O_WU2), bu2, dout, N);
        else
            update_kernel<false, false><<<(N + 127) / 128, 512, 0, stream>>>(
                ns, nullptr, dout, nullptr, nullptr, 0,
                (const u16*)(wsb + O_WU1), bu1, (const u16*)(wsb + O_WU2), bu2, dout, N);
    }
}